// Round 2
// baseline (1110.048 us; speedup 1.0000x reference)
//
#include <hip/hip_runtime.h>

#define NN 8192      // nodes
#define SS 20        // seq len
#define DD 256       // feat dim = H
#define RGATE 1024   // 4H
#define KKD 512      // D + H

typedef __attribute__((ext_vector_type(8))) short short8;
typedef __attribute__((ext_vector_type(4))) float f32x4;

__device__ __forceinline__ unsigned short f2bf(float f) {
    unsigned int u = __float_as_uint(f);
    u += 0x7FFFu + ((u >> 16) & 1u);   // round-to-nearest-even
    return (unsigned short)(u >> 16);
}

__device__ __forceinline__ void async_copy16(const void* g, void* l) {
    __builtin_amdgcn_global_load_lds(
        (const __attribute__((address_space(1))) void*)g,
        (__attribute__((address_space(3))) void*)l, 16, 0, 0);
}

__device__ __forceinline__ float sigm(float x) { return 1.0f / (1.0f + __expf(-x)); }
__device__ __forceinline__ float tanh_(float x) { return 2.0f / (1.0f + __expf(-2.0f * x)) - 1.0f; }

// ---------------------------------------------------------------------------
// Weight repack: Wcat[dir][r'][k], r' = 4*j + gate; k<256 -> w_ih, else w_hh.
// ---------------------------------------------------------------------------
__global__ void convert_w(const float* __restrict__ wihf, const float* __restrict__ whhf,
                          const float* __restrict__ bf,   const float* __restrict__ wihb,
                          const float* __restrict__ whhb, const float* __restrict__ bb,
                          unsigned short* __restrict__ Wcat, float* __restrict__ bperm) {
    const int idx = blockIdx.x * 256 + threadIdx.x;   // < 2*1024*512
    const int dir = idx >> 19;
    const int rem = idx & ((1 << 19) - 1);
    const int rp  = rem >> 9;          // r' in [0,1024)
    const int k   = rem & 511;
    const int j   = rp >> 2, gi = rp & 3;
    const int r   = gi * 256 + j;      // original row (PyTorch i,f,g,o blocks)
    const float* wih = dir ? wihb : wihf;
    const float* whh = dir ? whhb : whhf;
    const float v = (k < 256) ? wih[r * 256 + k] : whh[r * 256 + (k - 256)];
    Wcat[idx] = f2bf(v);
    if (k == 0) {
        const float* b = dir ? bb : bf;
        bperm[dir * 1024 + rp] = b[r];
    }
}

// ---------------------------------------------------------------------------
// Gather neighbor embeddings to bf16: X[t][n][256]. 4 waves/block, 1 row/wave.
// ---------------------------------------------------------------------------
__global__ __launch_bounds__(256) void gather_x(const float* __restrict__ emb,
                                                const int* __restrict__ idx,
                                                unsigned short* __restrict__ X) {
    const int w = threadIdx.x >> 6, lane = threadIdx.x & 63;
    #pragma unroll 4
    for (int i = 0; i < 16; ++i) {
        const int rid = (blockIdx.x * 16 + i) * 4 + w;   // 0..163839 = n*SS+t
        const int n = rid / SS, t = rid - n * SS;
        const int row = idx[rid];
        const float4 v = ((const float4*)(emb + (size_t)row * DD))[lane];
        ushort4 o;
        o.x = f2bf(v.x); o.y = f2bf(v.y); o.z = f2bf(v.z); o.w = f2bf(v.w);
        ((ushort4*)(X + ((size_t)t * NN + n) * DD))[lane] = o;
    }
}

// ---------------------------------------------------------------------------
// PERSISTENT bidirectional LSTM: one kernel runs all 20 steps.
// Grid 256 = 1 block/CU (96 KB LDS forces 1/CU -> all blocks co-resident,
// no cooperative launch needed). The dependency graph decomposes into 64
// independent chains: block (dir,mslab,nblk) at step s+1 needs h rows
// m0..m0+255 (all cols), produced by its 3 nblk-siblings + itself at step s.
// Siblings share b&7 -> same XCD/L2. Handshake: per-(dir,mslab,s) flag,
// release-add after epilogue, acquire-spin before staging hprev (at r==6,
// so the wait hides under rounds 0-7 which only consume X). The same spin
// (flags[s-1]==4, posted after siblings' staging reads of ping[(s+1)&1])
// closes the WAR hazard on the h ping-pong overwrite at step s+2.
// s==0: h=0, c=0 -> only 8 rounds (x-half), no c-load, no memsets needed.
// K-loop: 3-deep LDS pipeline, counted vmcnt(4), no main-loop drain (R1).
// LDS 64-B rows, seg' = quad ^ ((row>>1)&3): 2-way = free.
// ---------------------------------------------------------------------------
__global__ __launch_bounds__(512, 2) void lstm_persist(
    const unsigned short* __restrict__ X,      // [SS][NN][256] bf16
    const unsigned short* __restrict__ Wcat,   // [2][1024][512] bf16
    const float* __restrict__ bperm,           // [2][1024]
    unsigned short* __restrict__ hping,        // [2 ping][2 dir][NN][256] bf16
    float* __restrict__ cstate,                // [2 dir][NN][256] f32
    float* __restrict__ hsum,                  // [NN] f32
    unsigned int* __restrict__ flags) {        // [2][32][SS]
    const int b     = blockIdx.x;              // 0..255
    const int dir   = b & 1;
    const int nblk  = (b >> 3) & 3;            // 0..3 (256 gate cols each)
    const int mslab = (((b & 7) >> 1) << 3) | (b >> 5);   // 0..31
    const int m0    = mslab * 256;
    const int n0    = nblk * 256;

    const unsigned short* W  = Wcat + (size_t)dir * RGATE * KKD;
    const float*          bp = bperm + dir * RGATE;
    float*                cdir = cstate + (size_t)dir * NN * 256;
    unsigned int*         myflags = flags + (dir * 32 + mslab) * SS;

    __shared__ __align__(16) char smem[98304];
    // A bufs: [0,48K) = 3 x 16K;  B bufs: [48K,96K) = 3 x 16K
    // epilogue scratch (34.8 KB) overlays [0, ...) after each K-loop.

    const int tid  = threadIdx.x;
    const int lane = tid & 63;
    const int w    = tid >> 6;        // 0..7
    const int wm   = w >> 1, wn = w & 1;
    const int quad = lane >> 4, l15 = lane & 15;
    const int jq   = lane & 3,  rl  = lane >> 2;

    // staging lane constants: lane covers LDS (row=base+(lane>>2), seg=lane&3)
    // which must hold global seg (lane&3) ^ ((row>>1)&3) = (lane&3)^((lane>>3)&3)
    const int srow  = lane >> 2;
    const int gsegl = (lane & 3) ^ ((lane >> 3) & 3);

    const int sA = (quad ^ ((l15 >> 1) & 3)) * 16;   // frag-read seg byte offset

    f32x4 acc[4][8];

    auto krnd = [&](int cb) {
        const char* Ab = smem + cb * 16384;
        const char* Bb = smem + 49152 + cb * 16384;
        short8 af[4], bfr[8];
        #pragma unroll
        for (int mt = 0; mt < 4; ++mt)
            af[mt] = *(const short8*)(Ab + (wm * 64 + mt * 16 + l15) * 64 + sA);
        #pragma unroll
        for (int nt = 0; nt < 8; ++nt)
            bfr[nt] = *(const short8*)(Bb + (wn * 128 + nt * 16 + l15) * 64 + sA);
        #pragma unroll
        for (int mt = 0; mt < 4; ++mt)
            #pragma unroll
            for (int nt = 0; nt < 8; ++nt)
                acc[mt][nt] = __builtin_amdgcn_mfma_f32_16x16x32_bf16(
                    af[mt], bfr[nt], acc[mt][nt], 0, 0, 0);
    };

    for (int s = 0; s < SS; ++s) {
        const int t = dir ? (SS - 1 - s) : s;
        const unsigned short* Xt    = X + (size_t)t * NN * DD;
        const unsigned short* hprev = hping + ((size_t)((s & 1) * 2 + dir)) * NN * 256;
        unsigned short*       hnext = hping + ((size_t)((((s + 1) & 1) * 2) + dir)) * NN * 256;
        const int nr = s ? 16 : 8;     // s==0: h==0, skip the h.W_hh half

        auto stage = [&](int rr, int buf) {
            const int k0 = (rr & 7) * 32;                  // col within X or h
            const unsigned short* Asrc = (rr < 8) ? Xt : hprev;
            char* Ad = smem + buf * 16384;
            char* Bd = smem + 49152 + buf * 16384;
            #pragma unroll
            for (int i = 0; i < 2; ++i) {
                const int lr = w * 32 + i * 16 + srow;     // local row 0..255
                async_copy16(Asrc + (size_t)(m0 + lr) * DD + k0 + gsegl * 8,
                             (void*)(Ad + (w * 32 + i * 16) * 64));
                async_copy16(W + (size_t)(n0 + lr) * KKD + rr * 32 + gsegl * 8,
                             (void*)(Bd + (w * 32 + i * 16) * 64));
            }
        };

        #pragma unroll
        for (int i = 0; i < 4; ++i)
            #pragma unroll
            for (int j = 0; j < 8; ++j) acc[i][j] = f32x4{0.f, 0.f, 0.f, 0.f};

        // ---- K-loop: 3-buffer pipeline, counted vmcnt, no main-loop drain ----
        stage(0, 0);
        stage(1, 1);
        int cb = 0, sb = 2;
        for (int r = 0; r < nr; ++r) {
            if (r + 1 < nr) { asm volatile("s_waitcnt vmcnt(4)" ::: "memory"); }
            else            { asm volatile("s_waitcnt vmcnt(0)" ::: "memory"); }
            asm volatile("s_barrier" ::: "memory");
            krnd(cb);
            if (r + 2 < nr) {
                if (r == 6 && s) {
                    // about to stage hprev: wait for all 4 group blocks' step s-1
                    const unsigned int* fl = myflags + (s - 1);
                    while (__hip_atomic_load(fl, __ATOMIC_ACQUIRE,
                                             __HIP_MEMORY_SCOPE_AGENT) != 4u)
                        __builtin_amdgcn_s_sleep(2);
                }
                stage(r + 2, sb);   // -> buf (r-1)%3; readers passed barrier above
            }
            cb = (cb == 2) ? 0 : cb + 1;
            sb = (sb == 2) ? 0 : sb + 1;
        }
        asm volatile("s_barrier" ::: "memory");            // epilogue overlays bufs

        // ---- epilogue: regroup gates (C/D -> unit-quads) via wave-private LDS ----
        float* my = (float*)smem + w * 1088;   // 16 x 68 floats per wave (34.8 KB)
        float hs[4] = {0.f, 0.f, 0.f, 0.f};

        #pragma unroll
        for (int half = 0; half < 2; ++half) {
            const int j0 = nblk * 64 + wn * 32 + half * 16 + jq * 4;  // global unit
            f32x4 bias4[4];
            #pragma unroll
            for (int jj = 0; jj < 4; ++jj)
                bias4[jj] = *(const f32x4*)(bp + 4 * (j0 + jj));
            #pragma unroll
            for (int mt = 0; mt < 4; ++mt) {
                #pragma unroll
                for (int nt = 0; nt < 4; ++nt) {
                    const int ntg = half * 4 + nt;
                    #pragma unroll
                    for (int v = 0; v < 4; ++v)
                        my[(quad * 4 + v) * 68 + nt * 16 + l15] = acc[mt][ntg][v];
                }
                asm volatile("s_waitcnt lgkmcnt(0)" ::: "memory");
                const int mg = m0 + wm * 64 + mt * 16 + rl;
                float* cptr = cdir + (size_t)mg * 256 + j0;
                f32x4 cold;
                if (s) cold = *(const f32x4*)cptr;
                else   cold = f32x4{0.f, 0.f, 0.f, 0.f};
                f32x4 cnew;
                ushort4 hp;
                float lsum = 0.f;
                #pragma unroll
                for (int jj = 0; jj < 4; ++jj) {
                    f32x4 g  = *(const f32x4*)(my + rl * 68 + (jq * 4 + jj) * 4);
                    f32x4 bb = bias4[jj];
                    const float gi = sigm(g.x + bb.x);   // i
                    const float gf = sigm(g.y + bb.y);   // f
                    const float gg = tanh_(g.z + bb.z);  // g
                    const float go = sigm(g.w + bb.w);   // o
                    const float cn = gf * cold[jj] + gi * gg;
                    cnew[jj] = cn;
                    const float hv = go * tanh_(cn);
                    lsum += hv;
                    ((unsigned short*)&hp)[jj] = f2bf(hv);
                }
                *(f32x4*)cptr = cnew;
                *(ushort4*)(hnext + (size_t)mg * 256 + j0) = hp;
                hs[mt] += lsum;
            }
        }

        // per-row partial sums -> one atomic per (wave, row)
        #pragma unroll
        for (int mt = 0; mt < 4; ++mt) {
            float v = hs[mt];
            v += __shfl_xor(v, 1);
            v += __shfl_xor(v, 2);
            if (jq == 0) atomicAdd(&hsum[m0 + wm * 64 + mt * 16 + rl], v);
        }

        // all waves' stores drained (vmcnt 0) at this barrier; then publish.
        __syncthreads();
        if (tid == 0)
            __hip_atomic_fetch_add(myflags + s, 1u, __ATOMIC_RELEASE,
                                   __HIP_MEMORY_SCOPE_AGENT);
    }
}

__global__ void bcast_out(const float* __restrict__ hsum, float* __restrict__ out) {
    const int n = blockIdx.x;
    const float v = hsum[n] * (1.0f / 512.0f);
    float2 p; p.x = v; p.y = v;
    ((float2*)(out + (size_t)n * 512))[threadIdx.x] = p;
}

extern "C" void kernel_launch(void* const* d_in, const int* in_sizes, int n_in,
                              void* d_out, int out_size, void* d_ws, size_t ws_size,
                              hipStream_t stream) {
    const float* emb  = (const float*)d_in[0];
    const float* wihf = (const float*)d_in[1];
    const float* whhf = (const float*)d_in[2];
    const float* bf   = (const float*)d_in[3];
    const float* wihb = (const float*)d_in[4];
    const float* whhb = (const float*)d_in[5];
    const float* bb   = (const float*)d_in[6];
    const int*   idx  = (const int*)d_in[7];
    float* out = (float*)d_out;

    // workspace layout (bytes)
    char* ws = (char*)d_ws;
    unsigned short* X     = (unsigned short*)(ws);               // 83,886,080  X[t][n][256] bf16
    unsigned short* Wcat  = (unsigned short*)(ws + 83886080);    //  2,097,152  [2][1024][512] bf16
    float*          bperm = (float*)(ws + 85983232);             //      8,192  [2][1024] f32
    unsigned short* hping = (unsigned short*)(ws + 85991424);    // 16,777,216  [2][2][8192][256] bf16
    float*          cst   = (float*)(ws + 102768640);            // 16,777,216  [2][8192][256] f32
    float*          hsum  = (float*)(ws + 119545856);            //     32,768  [8192] f32
    unsigned int*   flags = (unsigned int*)(ws + 119578624);     //      5,120  [2][32][20] u32
    // total: 119,583,744 B

    // only hsum + flags need zeroing (s==0 skips h/c reads entirely)
    hipMemsetAsync(hsum, 0, 32768 + 5120, stream);

    convert_w<<<4096, 256, 0, stream>>>(wihf, whhf, bf, wihb, whhb, bb, Wcat, bperm);
    gather_x<<<2560, 256, 0, stream>>>(emb, idx, X);
    lstm_persist<<<256, 512, 0, stream>>>(X, Wcat, bperm, hping, cst, hsum, flags);
    bcast_out<<<NN, 256, 0, stream>>>(hsum, out);
}

// Round 3
// 825.984 us; speedup vs baseline: 1.3439x; 1.3439x over previous
//
#include <hip/hip_runtime.h>

#define NN 8192      // nodes
#define SS 20        // seq len
#define DD 256       // feat dim = H
#define RGATE 1024   // 4H
#define KKD 512      // D + H

typedef __attribute__((ext_vector_type(8))) short short8;
typedef __attribute__((ext_vector_type(4))) float f32x4;

__device__ __forceinline__ unsigned short f2bf(float f) {
    unsigned int u = __float_as_uint(f);
    u += 0x7FFFu + ((u >> 16) & 1u);   // round-to-nearest-even
    return (unsigned short)(u >> 16);
}

__device__ __forceinline__ void async_copy16(const void* g, void* l) {
    __builtin_amdgcn_global_load_lds(
        (const __attribute__((address_space(1))) void*)g,
        (__attribute__((address_space(3))) void*)l, 16, 0, 0);
}

__device__ __forceinline__ float sigm(float x) { return 1.0f / (1.0f + __expf(-x)); }
__device__ __forceinline__ float tanh_(float x) { return 2.0f / (1.0f + __expf(-2.0f * x)) - 1.0f; }

// ---------------------------------------------------------------------------
// Weight repack: Wcat[dir][r'][k], r' = 4*j + gate; k<256 -> w_ih, else w_hh.
// ---------------------------------------------------------------------------
__global__ void convert_w(const float* __restrict__ wihf, const float* __restrict__ whhf,
                          const float* __restrict__ bf,   const float* __restrict__ wihb,
                          const float* __restrict__ whhb, const float* __restrict__ bb,
                          unsigned short* __restrict__ Wcat, float* __restrict__ bperm) {
    const int idx = blockIdx.x * 256 + threadIdx.x;   // < 2*1024*512
    const int dir = idx >> 19;
    const int rem = idx & ((1 << 19) - 1);
    const int rp  = rem >> 9;          // r' in [0,1024)
    const int k   = rem & 511;
    const int j   = rp >> 2, gi = rp & 3;
    const int r   = gi * 256 + j;      // original row (PyTorch i,f,g,o blocks)
    const float* wih = dir ? wihb : wihf;
    const float* whh = dir ? whhb : whhf;
    const float v = (k < 256) ? wih[r * 256 + k] : whh[r * 256 + (k - 256)];
    Wcat[idx] = f2bf(v);
    if (k == 0) {
        const float* b = dir ? bb : bf;
        bperm[dir * 1024 + rp] = b[r];
    }
}

// ---------------------------------------------------------------------------
// Gather neighbor embeddings to bf16: X[t][n][256]. 4 waves/block, 1 row/wave.
// ---------------------------------------------------------------------------
__global__ __launch_bounds__(256) void gather_x(const float* __restrict__ emb,
                                                const int* __restrict__ idx,
                                                unsigned short* __restrict__ X) {
    const int w = threadIdx.x >> 6, lane = threadIdx.x & 63;
    #pragma unroll 4
    for (int i = 0; i < 16; ++i) {
        const int rid = (blockIdx.x * 16 + i) * 4 + w;   // 0..163839 = n*SS+t
        const int n = rid / SS, t = rid - n * SS;
        const int row = idx[rid];
        const float4 v = ((const float4*)(emb + (size_t)row * DD))[lane];
        ushort4 o;
        o.x = f2bf(v.x); o.y = f2bf(v.y); o.z = f2bf(v.z); o.w = f2bf(v.w);
        ((ushort4*)(X + ((size_t)t * NN + n) * DD))[lane] = o;
    }
}

// ---------------------------------------------------------------------------
// One LSTM step, both dirs. Grid 256 (1 block/CU), 512 thr (8 waves).
// Block tile 256 rows x 256 gate cols; wave tile 64x128: acc[4][8].
// BK=32, 16 rounds (8 at s==0: h=c=0, x-half only -> memsets dropped).
// K-loop: 3-deep LDS pipeline, counted vmcnt(4) (R1, +65us), PLUS this
// round: m201-style phase split (T3+T5). Each round = 2 phases of 16 MFMA
// (nt 0-3 / nt 4-7); per phase: ds_read frags -> lgkmcnt(0) ->
// sched_barrier(0) [rule #18: compiler hoists reg-only MFMA past inline-asm
// waits] -> setprio(1) -> 16 MFMA -> setprio(0). Mid-round s_barrier at the
// phase boundary (barrier density 1 per K=16 ~ m201's). stage(r+2) issued
// inside phase A so DMA issue hides under compute. Persistent-kernel variant
// (R2) REGRESSED (13.6% MfmaUtil, lockstep handshake) -> reverted to
// 20 launches.
// LDS 64-B rows (4x16B segs), seg' = quad ^ ((row>>1)&3): 2-way = free.
// h/c in global, XCD-L2-resident via decode: xcd=b&7, dir=b&1 (W per parity),
// mslab tied to XCD-pair so A panels shared by the 4 nblk blocks on-XCD.
// ---------------------------------------------------------------------------
__global__ __launch_bounds__(512, 2) void lstm_step(
    const unsigned short* __restrict__ X,      // [SS][NN][256] bf16
    const unsigned short* __restrict__ Wcat,   // [2][1024][512] bf16
    const float* __restrict__ bperm,           // [2][1024]
    unsigned short* __restrict__ hping,        // [2 ping][2 dir][NN][256] bf16
    float* __restrict__ cstate,                // [2 dir][NN][256] f32
    float* __restrict__ hsum,                  // [NN] f32
    int s) {
    const int b     = blockIdx.x;              // 0..255
    const int dir   = b & 1;
    const int nblk  = (b >> 3) & 3;            // 0..3 (256 gate cols each)
    const int mslab = (((b & 7) >> 1) << 3) | (b >> 5);   // 0..31
    const int m0    = mslab * 256;
    const int n0    = nblk * 256;

    const int t = dir ? (SS - 1 - s) : s;
    const unsigned short* Xt    = X + (size_t)t * NN * DD;
    const unsigned short* hprev = hping + ((size_t)((s & 1) * 2 + dir)) * NN * 256;
    unsigned short*       hnext = hping + ((size_t)((((s + 1) & 1) * 2) + dir)) * NN * 256;
    const unsigned short* W     = Wcat + (size_t)dir * RGATE * KKD;
    const float*          bp    = bperm + dir * RGATE;
    float*                cdir  = cstate + (size_t)dir * NN * 256;

    __shared__ __align__(16) char smem[98304];
    // A bufs: [0,48K) = 3 x 16K;  B bufs: [48K,96K) = 3 x 16K
    // epilogue scratch (34.8 KB) overlays [0, ...) after the K-loop.

    const int tid  = threadIdx.x;
    const int lane = tid & 63;
    const int w    = tid >> 6;        // 0..7
    const int wm   = w >> 1, wn = w & 1;
    const int quad = lane >> 4, l15 = lane & 15;
    const int jq   = lane & 3,  rl  = lane >> 2;

    // staging lane constants: lane covers LDS (row=base+(lane>>2), seg=lane&3)
    // which must hold global seg (lane&3) ^ ((row>>1)&3) = (lane&3)^((lane>>3)&3)
    const int srow  = lane >> 2;
    const int gsegl = (lane & 3) ^ ((lane >> 3) & 3);

    const int nr = s ? 16 : 8;        // s==0: h==0, skip the h.W_hh half

    auto stage = [&](int rr, int buf) {
        const int k0 = (rr & 7) * 32;                      // col within X or h
        const unsigned short* Asrc = (rr < 8) ? Xt : hprev;
        char* Ad = smem + buf * 16384;
        char* Bd = smem + 49152 + buf * 16384;
        #pragma unroll
        for (int i = 0; i < 2; ++i) {
            const int lr = w * 32 + i * 16 + srow;         // local row 0..255
            async_copy16(Asrc + (size_t)(m0 + lr) * DD + k0 + gsegl * 8,
                         (void*)(Ad + (w * 32 + i * 16) * 64));
            async_copy16(W + (size_t)(n0 + lr) * KKD + rr * 32 + gsegl * 8,
                         (void*)(Bd + (w * 32 + i * 16) * 64));
        }
    };

    f32x4 acc[4][8];
    #pragma unroll
    for (int i = 0; i < 4; ++i)
        #pragma unroll
        for (int j = 0; j < 8; ++j) acc[i][j] = f32x4{0.f, 0.f, 0.f, 0.f};

    const int sA = (quad ^ ((l15 >> 1) & 3)) * 16;   // frag-read seg byte offset

    // ---- K-loop: 3-buffer pipeline, counted vmcnt, 2-phase rounds ----
    stage(0, 0);
    stage(1, 1);
    int cb = 0, sb = 2;
    for (int r = 0; r < nr; ++r) {
        if (r + 1 < nr) { asm volatile("s_waitcnt vmcnt(4)" ::: "memory"); }
        else            { asm volatile("s_waitcnt vmcnt(0)" ::: "memory"); }
        asm volatile("s_barrier" ::: "memory");    // buf cb proven for all waves
        __builtin_amdgcn_sched_barrier(0);
        const char* Ab = smem + cb * 16384;
        const char* Bb = smem + 49152 + cb * 16384;
        short8 af[4], bfr[4];
        // ---- phase A: af + bfr[0..3], stage, 16 MFMA ----
        #pragma unroll
        for (int mt = 0; mt < 4; ++mt)
            af[mt] = *(const short8*)(Ab + (wm * 64 + mt * 16 + l15) * 64 + sA);
        #pragma unroll
        for (int nt = 0; nt < 4; ++nt)
            bfr[nt] = *(const short8*)(Bb + (wn * 128 + nt * 16 + l15) * 64 + sA);
        if (r + 2 < nr) stage(r + 2, sb);          // DMA issue hides under MFMA
        asm volatile("s_waitcnt lgkmcnt(0)" ::: "memory");
        __builtin_amdgcn_sched_barrier(0);
        __builtin_amdgcn_s_setprio(1);
        #pragma unroll
        for (int mt = 0; mt < 4; ++mt)
            #pragma unroll
            for (int nt = 0; nt < 4; ++nt)
                acc[mt][nt] = __builtin_amdgcn_mfma_f32_16x16x32_bf16(
                    af[mt], bfr[nt], acc[mt][nt], 0, 0, 0);
        __builtin_amdgcn_s_setprio(0);
        __builtin_amdgcn_sched_barrier(0);
        asm volatile("s_barrier" ::: "memory");    // phase boundary
        // ---- phase B: bfr[4..7], 16 MFMA ----
        #pragma unroll
        for (int nt = 0; nt < 4; ++nt)
            bfr[nt] = *(const short8*)(Bb + (wn * 128 + (nt + 4) * 16 + l15) * 64 + sA);
        asm volatile("s_waitcnt lgkmcnt(0)" ::: "memory");
        __builtin_amdgcn_sched_barrier(0);
        __builtin_amdgcn_s_setprio(1);
        #pragma unroll
        for (int mt = 0; mt < 4; ++mt)
            #pragma unroll
            for (int nt = 0; nt < 4; ++nt)
                acc[mt][nt + 4] = __builtin_amdgcn_mfma_f32_16x16x32_bf16(
                    af[mt], bfr[nt], acc[mt][nt + 4], 0, 0, 0);
        __builtin_amdgcn_s_setprio(0);
        __builtin_amdgcn_sched_barrier(0);
        cb = (cb == 2) ? 0 : cb + 1;
        sb = (sb == 2) ? 0 : sb + 1;
    }
    asm volatile("s_barrier" ::: "memory");        // epilogue overlays bufs

    // ---- epilogue: regroup gates (C/D -> unit-quads) via wave-private LDS ----
    float* my = (float*)smem + w * 1088;   // 16 x 68 floats per wave (34.8 KB)
    float hs[4] = {0.f, 0.f, 0.f, 0.f};

    #pragma unroll
    for (int half = 0; half < 2; ++half) {
        const int j0 = nblk * 64 + wn * 32 + half * 16 + jq * 4;  // global unit
        f32x4 bias4[4];
        #pragma unroll
        for (int jj = 0; jj < 4; ++jj)
            bias4[jj] = *(const f32x4*)(bp + 4 * (j0 + jj));
        #pragma unroll
        for (int mt = 0; mt < 4; ++mt) {
            #pragma unroll
            for (int nt = 0; nt < 4; ++nt) {
                const int ntg = half * 4 + nt;
                #pragma unroll
                for (int v = 0; v < 4; ++v)
                    my[(quad * 4 + v) * 68 + nt * 16 + l15] = acc[mt][ntg][v];
            }
            asm volatile("s_waitcnt lgkmcnt(0)" ::: "memory");
            const int mg = m0 + wm * 64 + mt * 16 + rl;
            float* cptr = cdir + (size_t)mg * 256 + j0;
            f32x4 cold;
            if (s) cold = *(const f32x4*)cptr;
            else   cold = f32x4{0.f, 0.f, 0.f, 0.f};
            f32x4 cnew;
            ushort4 hp;
            float lsum = 0.f;
            #pragma unroll
            for (int jj = 0; jj < 4; ++jj) {
                f32x4 g  = *(const f32x4*)(my + rl * 68 + (jq * 4 + jj) * 4);
                f32x4 bb = bias4[jj];
                const float gi = sigm(g.x + bb.x);   // i
                const float gf = sigm(g.y + bb.y);   // f
                const float gg = tanh_(g.z + bb.z);  // g
                const float go = sigm(g.w + bb.w);   // o
                const float cn = gf * cold[jj] + gi * gg;
                cnew[jj] = cn;
                const float hv = go * tanh_(cn);
                lsum += hv;
                ((unsigned short*)&hp)[jj] = f2bf(hv);
            }
            *(f32x4*)cptr = cnew;
            *(ushort4*)(hnext + (size_t)mg * 256 + j0) = hp;
            hs[mt] += lsum;
        }
    }

    // per-row partial sums -> one atomic per (wave, row)
    #pragma unroll
    for (int mt = 0; mt < 4; ++mt) {
        float v = hs[mt];
        v += __shfl_xor(v, 1);
        v += __shfl_xor(v, 2);
        if (jq == 0) atomicAdd(&hsum[m0 + wm * 64 + mt * 16 + rl], v);
    }
}

__global__ void bcast_out(const float* __restrict__ hsum, float* __restrict__ out) {
    const int n = blockIdx.x;
    const float v = hsum[n] * (1.0f / 512.0f);
    float2 p; p.x = v; p.y = v;
    ((float2*)(out + (size_t)n * 512))[threadIdx.x] = p;
}

extern "C" void kernel_launch(void* const* d_in, const int* in_sizes, int n_in,
                              void* d_out, int out_size, void* d_ws, size_t ws_size,
                              hipStream_t stream) {
    const float* emb  = (const float*)d_in[0];
    const float* wihf = (const float*)d_in[1];
    const float* whhf = (const float*)d_in[2];
    const float* bf   = (const float*)d_in[3];
    const float* wihb = (const float*)d_in[4];
    const float* whhb = (const float*)d_in[5];
    const float* bb   = (const float*)d_in[6];
    const int*   idx  = (const int*)d_in[7];
    float* out = (float*)d_out;

    // workspace layout (bytes)
    char* ws = (char*)d_ws;
    unsigned short* X     = (unsigned short*)(ws);               // 83,886,080  X[t][n][256] bf16
    unsigned short* Wcat  = (unsigned short*)(ws + 83886080);    //  2,097,152  [2][1024][512] bf16
    float*          bperm = (float*)(ws + 85983232);             //      8,192  [2][1024] f32
    unsigned short* hping = (unsigned short*)(ws + 85991424);    // 16,777,216  [2][2][8192][256] bf16
    float*          cst   = (float*)(ws + 102768640);            // 16,777,216  [2][8192][256] f32
    float*          hsum  = (float*)(ws + 119545856);            //     32,768  [8192] f32
    // total: 119,578,624 B

    // s==0 skips all h/c reads -> only hsum needs zeroing
    hipMemsetAsync(hsum, 0, 32768, stream);

    convert_w<<<4096, 256, 0, stream>>>(wihf, whhf, bf, wihb, whhb, bb, Wcat, bperm);
    gather_x<<<2560, 256, 0, stream>>>(emb, idx, X);
    for (int s = 0; s < SS; ++s)
        lstm_step<<<256, 512, 0, stream>>>(X, Wcat, bperm, hping, cst, hsum, s);
    bcast_out<<<NN, 256, 0, stream>>>(hsum, out);
}

// Round 4
// 802.518 us; speedup vs baseline: 1.3832x; 1.0292x over previous
//
#include <hip/hip_runtime.h>

#define NN 8192      // nodes
#define SS 20        // seq len
#define DD 256       // feat dim = H
#define RGATE 1024   // 4H
#define KKD 512      // D + H

typedef __attribute__((ext_vector_type(8))) short short8;
typedef __attribute__((ext_vector_type(4))) float f32x4;

__device__ __forceinline__ unsigned short f2bf(float f) {
    unsigned int u = __float_as_uint(f);
    u += 0x7FFFu + ((u >> 16) & 1u);   // round-to-nearest-even
    return (unsigned short)(u >> 16);
}

__device__ __forceinline__ void async_copy16(const void* g, void* l) {
    __builtin_amdgcn_global_load_lds(
        (const __attribute__((address_space(1))) void*)g,
        (__attribute__((address_space(3))) void*)l, 16, 0, 0);
}

__device__ __forceinline__ float sigm(float x) { return 1.0f / (1.0f + __expf(-x)); }
__device__ __forceinline__ float tanh_(float x) { return 2.0f / (1.0f + __expf(-2.0f * x)) - 1.0f; }

// ---------------------------------------------------------------------------
// Weight repack: Wcat[dir][r'][k], r' = 4*j + gate; k<256 -> w_ih, else w_hh.
// ---------------------------------------------------------------------------
__global__ void convert_w(const float* __restrict__ wihf, const float* __restrict__ whhf,
                          const float* __restrict__ bf,   const float* __restrict__ wihb,
                          const float* __restrict__ whhb, const float* __restrict__ bb,
                          unsigned short* __restrict__ Wcat, float* __restrict__ bperm) {
    const int idx = blockIdx.x * 256 + threadIdx.x;   // < 2*1024*512
    const int dir = idx >> 19;
    const int rem = idx & ((1 << 19) - 1);
    const int rp  = rem >> 9;          // r' in [0,1024)
    const int k   = rem & 511;
    const int j   = rp >> 2, gi = rp & 3;
    const int r   = gi * 256 + j;      // original row (PyTorch i,f,g,o blocks)
    const float* wih = dir ? wihb : wihf;
    const float* whh = dir ? whhb : whhf;
    const float v = (k < 256) ? wih[r * 256 + k] : whh[r * 256 + (k - 256)];
    Wcat[idx] = f2bf(v);
    if (k == 0) {
        const float* b = dir ? bb : bf;
        bperm[dir * 1024 + rp] = b[r];
    }
}

// ---------------------------------------------------------------------------
// Gather neighbor embeddings to bf16: X[t][n][256]. 4 waves/block, 1 row/wave.
// ---------------------------------------------------------------------------
__global__ __launch_bounds__(256) void gather_x(const float* __restrict__ emb,
                                                const int* __restrict__ idx,
                                                unsigned short* __restrict__ X) {
    const int w = threadIdx.x >> 6, lane = threadIdx.x & 63;
    #pragma unroll 4
    for (int i = 0; i < 16; ++i) {
        const int rid = (blockIdx.x * 16 + i) * 4 + w;   // 0..163839 = n*SS+t
        const int n = rid / SS, t = rid - n * SS;
        const int row = idx[rid];
        const float4 v = ((const float4*)(emb + (size_t)row * DD))[lane];
        ushort4 o;
        o.x = f2bf(v.x); o.y = f2bf(v.y); o.z = f2bf(v.z); o.w = f2bf(v.w);
        ((ushort4*)(X + ((size_t)t * NN + n) * DD))[lane] = o;
    }
}

// ---------------------------------------------------------------------------
// One LSTM step, both dirs. Grid 256 (1 block/CU), 512 thr (8 waves).
// Block tile 256 rows x 256 gate cols; wave tile 64x128: acc[4][8].
// BK=32, 16 rounds (8 at s==0: h=c=0, x-half only; memsets dropped).
// K-loop: R1's proven structure (counted vmcnt, no drain, no phase split --
// R3's phase-split/setprio REGRESSED: no wave-role diversity at 2 waves/SIMD,
// mid-round barrier serialized; R2 persistent REGRESSED: handshake lockstep).
// This round: pipeline depth 3 -> 4 (LDS 128 KB, still 1 block/CU):
// stage(r+3) issued in round r, steady-state s_waitcnt vmcnt(8) (2 stages x
// 4 copies/lane in flight), cover for stage(r) ~3 rounds > HBM-miss latency
// (X panel is the one HBM-cold stream each step).
// LDS 64-B rows (4x16B segs), seg' = quad ^ ((row>>1)&3): 2-way = free.
// h/c in global, XCD-L2-resident via decode: xcd=b&7, dir=b&1 (W per parity),
// mslab tied to XCD-pair so A panels shared by the 4 nblk blocks on-XCD.
// ---------------------------------------------------------------------------
__global__ __launch_bounds__(512, 2) void lstm_step(
    const unsigned short* __restrict__ X,      // [SS][NN][256] bf16
    const unsigned short* __restrict__ Wcat,   // [2][1024][512] bf16
    const float* __restrict__ bperm,           // [2][1024]
    unsigned short* __restrict__ hping,        // [2 ping][2 dir][NN][256] bf16
    float* __restrict__ cstate,                // [2 dir][NN][256] f32
    float* __restrict__ hsum,                  // [NN] f32
    int s) {
    const int b     = blockIdx.x;              // 0..255
    const int dir   = b & 1;
    const int nblk  = (b >> 3) & 3;            // 0..3 (256 gate cols each)
    const int mslab = (((b & 7) >> 1) << 3) | (b >> 5);   // 0..31
    const int m0    = mslab * 256;
    const int n0    = nblk * 256;

    const int t = dir ? (SS - 1 - s) : s;
    const unsigned short* Xt    = X + (size_t)t * NN * DD;
    const unsigned short* hprev = hping + ((size_t)((s & 1) * 2 + dir)) * NN * 256;
    unsigned short*       hnext = hping + ((size_t)((((s + 1) & 1) * 2) + dir)) * NN * 256;
    const unsigned short* W     = Wcat + (size_t)dir * RGATE * KKD;
    const float*          bp    = bperm + dir * RGATE;
    float*                cdir  = cstate + (size_t)dir * NN * 256;

    __shared__ __align__(16) char smem[131072];
    // A bufs: [0,64K) = 4 x 16K;  B bufs: [64K,128K) = 4 x 16K
    // epilogue scratch (34.8 KB) overlays [0, ...) after the K-loop.

    const int tid  = threadIdx.x;
    const int lane = tid & 63;
    const int w    = tid >> 6;        // 0..7
    const int wm   = w >> 1, wn = w & 1;
    const int quad = lane >> 4, l15 = lane & 15;
    const int jq   = lane & 3,  rl  = lane >> 2;

    // staging lane constants: lane covers LDS (row=base+(lane>>2), seg=lane&3)
    // which must hold global seg (lane&3) ^ ((row>>1)&3) = (lane&3)^((lane>>3)&3)
    const int srow  = lane >> 2;
    const int gsegl = (lane & 3) ^ ((lane >> 3) & 3);

    const int nr = s ? 16 : 8;        // s==0: h==0, skip the h.W_hh half

    auto stage = [&](int rr, int buf) {
        const int k0 = (rr & 7) * 32;                      // col within X or h
        const unsigned short* Asrc = (rr < 8) ? Xt : hprev;
        char* Ad = smem + buf * 16384;
        char* Bd = smem + 65536 + buf * 16384;
        #pragma unroll
        for (int i = 0; i < 2; ++i) {
            const int lr = w * 32 + i * 16 + srow;         // local row 0..255
            async_copy16(Asrc + (size_t)(m0 + lr) * DD + k0 + gsegl * 8,
                         (void*)(Ad + (w * 32 + i * 16) * 64));
            async_copy16(W + (size_t)(n0 + lr) * KKD + rr * 32 + gsegl * 8,
                         (void*)(Bd + (w * 32 + i * 16) * 64));
        }
    };

    f32x4 acc[4][8];
    #pragma unroll
    for (int i = 0; i < 4; ++i)
        #pragma unroll
        for (int j = 0; j < 8; ++j) acc[i][j] = f32x4{0.f, 0.f, 0.f, 0.f};

    const int sA = (quad ^ ((l15 >> 1) & 3)) * 16;   // frag-read seg byte offset

    auto krnd = [&](int cb) {
        const char* Ab = smem + cb * 16384;
        const char* Bb = smem + 65536 + cb * 16384;
        short8 af[4], bfr[8];
        #pragma unroll
        for (int mt = 0; mt < 4; ++mt)
            af[mt] = *(const short8*)(Ab + (wm * 64 + mt * 16 + l15) * 64 + sA);
        #pragma unroll
        for (int nt = 0; nt < 8; ++nt)
            bfr[nt] = *(const short8*)(Bb + (wn * 128 + nt * 16 + l15) * 64 + sA);
        #pragma unroll
        for (int mt = 0; mt < 4; ++mt)
            #pragma unroll
            for (int nt = 0; nt < 8; ++nt)
                acc[mt][nt] = __builtin_amdgcn_mfma_f32_16x16x32_bf16(
                    af[mt], bfr[nt], acc[mt][nt], 0, 0, 0);
    };

    // ---- K-loop: 4-buffer pipeline, counted vmcnt, no main-loop drain ----
    // vmcnt proof at top of round r: issued stages 0..min(r+2, nr-1); allowed
    // outstanding = those with index > r -> k = min(r+2,nr-1)-r stages = 4k ops.
    stage(0, 0);
    stage(1, 1);
    stage(2, 2);
    int cb = 0, sb = 3;
    for (int r = 0; r < nr; ++r) {
        if (r + 3 <= nr - 1)      { asm volatile("s_waitcnt vmcnt(8)" ::: "memory"); }
        else if (r + 2 <= nr - 1) { asm volatile("s_waitcnt vmcnt(4)" ::: "memory"); }
        else                      { asm volatile("s_waitcnt vmcnt(0)" ::: "memory"); }
        asm volatile("s_barrier" ::: "memory");   // buf cb proven for all waves
        krnd(cb);
        if (r + 3 < nr) stage(r + 3, sb);   // -> buf (r-1)&3; readers passed barrier
        cb = (cb + 1) & 3;
        sb = (sb + 1) & 3;
    }
    asm volatile("s_barrier" ::: "memory");       // epilogue overlays bufs

    // ---- epilogue: regroup gates (C/D -> unit-quads) via wave-private LDS ----
    float* my = (float*)smem + w * 1088;   // 16 x 68 floats per wave (34.8 KB)
    float hs[4] = {0.f, 0.f, 0.f, 0.f};

    #pragma unroll
    for (int half = 0; half < 2; ++half) {
        const int j0 = nblk * 64 + wn * 32 + half * 16 + jq * 4;  // global unit
        f32x4 bias4[4];
        #pragma unroll
        for (int jj = 0; jj < 4; ++jj)
            bias4[jj] = *(const f32x4*)(bp + 4 * (j0 + jj));
        #pragma unroll
        for (int mt = 0; mt < 4; ++mt) {
            #pragma unroll
            for (int nt = 0; nt < 4; ++nt) {
                const int ntg = half * 4 + nt;
                #pragma unroll
                for (int v = 0; v < 4; ++v)
                    my[(quad * 4 + v) * 68 + nt * 16 + l15] = acc[mt][ntg][v];
            }
            asm volatile("s_waitcnt lgkmcnt(0)" ::: "memory");
            const int mg = m0 + wm * 64 + mt * 16 + rl;
            float* cptr = cdir + (size_t)mg * 256 + j0;
            f32x4 cold;
            if (s) cold = *(const f32x4*)cptr;
            else   cold = f32x4{0.f, 0.f, 0.f, 0.f};
            f32x4 cnew;
            ushort4 hp;
            float lsum = 0.f;
            #pragma unroll
            for (int jj = 0; jj < 4; ++jj) {
                f32x4 g  = *(const f32x4*)(my + rl * 68 + (jq * 4 + jj) * 4);
                f32x4 bb = bias4[jj];
                const float gi = sigm(g.x + bb.x);   // i
                const float gf = sigm(g.y + bb.y);   // f
                const float gg = tanh_(g.z + bb.z);  // g
                const float go = sigm(g.w + bb.w);   // o
                const float cn = gf * cold[jj] + gi * gg;
                cnew[jj] = cn;
                const float hv = go * tanh_(cn);
                lsum += hv;
                ((unsigned short*)&hp)[jj] = f2bf(hv);
            }
            *(f32x4*)cptr = cnew;
            *(ushort4*)(hnext + (size_t)mg * 256 + j0) = hp;
            hs[mt] += lsum;
        }
    }

    // per-row partial sums -> one atomic per (wave, row)
    #pragma unroll
    for (int mt = 0; mt < 4; ++mt) {
        float v = hs[mt];
        v += __shfl_xor(v, 1);
        v += __shfl_xor(v, 2);
        if (jq == 0) atomicAdd(&hsum[m0 + wm * 64 + mt * 16 + rl], v);
    }
}

__global__ void bcast_out(const float* __restrict__ hsum, float* __restrict__ out) {
    const int n = blockIdx.x;
    const float v = hsum[n] * (1.0f / 512.0f);
    float2 p; p.x = v; p.y = v;
    ((float2*)(out + (size_t)n * 512))[threadIdx.x] = p;
}

extern "C" void kernel_launch(void* const* d_in, const int* in_sizes, int n_in,
                              void* d_out, int out_size, void* d_ws, size_t ws_size,
                              hipStream_t stream) {
    const float* emb  = (const float*)d_in[0];
    const float* wihf = (const float*)d_in[1];
    const float* whhf = (const float*)d_in[2];
    const float* bf   = (const float*)d_in[3];
    const float* wihb = (const float*)d_in[4];
    const float* whhb = (const float*)d_in[5];
    const float* bb   = (const float*)d_in[6];
    const int*   idx  = (const int*)d_in[7];
    float* out = (float*)d_out;

    // workspace layout (bytes)
    char* ws = (char*)d_ws;
    unsigned short* X     = (unsigned short*)(ws);               // 83,886,080  X[t][n][256] bf16
    unsigned short* Wcat  = (unsigned short*)(ws + 83886080);    //  2,097,152  [2][1024][512] bf16
    float*          bperm = (float*)(ws + 85983232);             //      8,192  [2][1024] f32
    unsigned short* hping = (unsigned short*)(ws + 85991424);    // 16,777,216  [2][2][8192][256] bf16
    float*          cst   = (float*)(ws + 102768640);            // 16,777,216  [2][8192][256] f32
    float*          hsum  = (float*)(ws + 119545856);            //     32,768  [8192] f32
    // total: 119,578,624 B

    // s==0 skips all h/c reads -> only hsum needs zeroing
    hipMemsetAsync(hsum, 0, 32768, stream);

    convert_w<<<4096, 256, 0, stream>>>(wihf, whhf, bf, wihb, whhb, bb, Wcat, bperm);
    gather_x<<<2560, 256, 0, stream>>>(emb, idx, X);
    for (int s = 0; s < SS; ++s)
        lstm_step<<<256, 512, 0, stream>>>(X, Wcat, bperm, hping, cst, hsum, s);
    bcast_out<<<NN, 256, 0, stream>>>(hsum, out);
}

// Round 5
// 773.349 us; speedup vs baseline: 1.4354x; 1.0377x over previous
//
#include <hip/hip_runtime.h>

#define NN 8192      // nodes
#define SS 20        // seq len
#define DD 256       // feat dim = H
#define RGATE 1024   // 4H
#define KKD 512      // D + H

typedef __attribute__((ext_vector_type(8))) short short8;
typedef __attribute__((ext_vector_type(4))) float f32x4;

__device__ __forceinline__ unsigned short f2bf(float f) {
    unsigned int u = __float_as_uint(f);
    u += 0x7FFFu + ((u >> 16) & 1u);   // round-to-nearest-even
    return (unsigned short)(u >> 16);
}

__device__ __forceinline__ void async_copy16(const void* g, void* l) {
    __builtin_amdgcn_global_load_lds(
        (const __attribute__((address_space(1))) void*)g,
        (__attribute__((address_space(3))) void*)l, 16, 0, 0);
}

__device__ __forceinline__ float sigm(float x) { return 1.0f / (1.0f + __expf(-x)); }
__device__ __forceinline__ float tanh_(float x) { return 2.0f / (1.0f + __expf(-2.0f * x)) - 1.0f; }

// ---------------------------------------------------------------------------
// Weight repack: Wcat[dir][r'][k], r' = 4*j + gate; k<256 -> w_ih, else w_hh.
// ---------------------------------------------------------------------------
__global__ void convert_w(const float* __restrict__ wihf, const float* __restrict__ whhf,
                          const float* __restrict__ bf,   const float* __restrict__ wihb,
                          const float* __restrict__ whhb, const float* __restrict__ bb,
                          unsigned short* __restrict__ Wcat, float* __restrict__ bperm) {
    const int idx = blockIdx.x * 256 + threadIdx.x;   // < 2*1024*512
    const int dir = idx >> 19;
    const int rem = idx & ((1 << 19) - 1);
    const int rp  = rem >> 9;          // r' in [0,1024)
    const int k   = rem & 511;
    const int j   = rp >> 2, gi = rp & 3;
    const int r   = gi * 256 + j;      // original row (PyTorch i,f,g,o blocks)
    const float* wih = dir ? wihb : wihf;
    const float* whh = dir ? whhb : whhf;
    const float v = (k < 256) ? wih[r * 256 + k] : whh[r * 256 + (k - 256)];
    Wcat[idx] = f2bf(v);
    if (k == 0) {
        const float* b = dir ? bb : bf;
        bperm[dir * 1024 + rp] = b[r];
    }
}

// ---------------------------------------------------------------------------
// Gather neighbor embeddings to bf16: X[t][n][256]. 4 waves/block, 1 row/wave.
// ---------------------------------------------------------------------------
__global__ __launch_bounds__(256) void gather_x(const float* __restrict__ emb,
                                                const int* __restrict__ idx,
                                                unsigned short* __restrict__ X) {
    const int w = threadIdx.x >> 6, lane = threadIdx.x & 63;
    #pragma unroll 4
    for (int i = 0; i < 16; ++i) {
        const int rid = (blockIdx.x * 16 + i) * 4 + w;   // 0..163839 = n*SS+t
        const int n = rid / SS, t = rid - n * SS;
        const int row = idx[rid];
        const float4 v = ((const float4*)(emb + (size_t)row * DD))[lane];
        ushort4 o;
        o.x = f2bf(v.x); o.y = f2bf(v.y); o.z = f2bf(v.z); o.w = f2bf(v.w);
        ((ushort4*)(X + ((size_t)t * NN + n) * DD))[lane] = o;
    }
}

// ---------------------------------------------------------------------------
// One LSTM step, both dirs. Grid 256 (1 block/CU), 512 thr (8 waves).
// Block tile 256 rows x 256 gate cols; wave tile 64x128: acc[4][8].
// BK=32; NR=16 rounds (NR=8 at s==0: h=c=0, x-half only; template FIRST
// keeps the hot path compile-time -- R4's runtime-nr loop with a vmcnt
// branch ladder REGRESSED ~56us vs R1's unrolled loop; this round keeps
// depth-4 but restores compile-time shape: uniform main-loop body
// (vmcnt(8) + stage always) + 3 explicit tail rounds with literal
// vmcnt(8)/(4)/(0) and literal buf indices 1,2,3 (NR%4==0 for both NR).
// Depth-4 cover: stage(r) issued 3 rounds (~950cyc) before its wait, >
// ~900cyc HBM-miss latency of the per-step-cold X panel (R1's 3-deep
// covered only ~620cyc).
// R2 persistent REGRESSED (handshake lockstep); R3 phase-split/setprio
// REGRESSED (no wave-role diversity at 2 waves/SIMD) -- both reverted.
// LDS 64-B rows (4x16B segs), seg' = quad ^ ((row>>1)&3): 2-way = free.
// h/c in global, XCD-L2-resident via decode: xcd=b&7, dir=b&1 (W per parity),
// mslab tied to XCD-pair so A panels shared by the 4 nblk blocks on-XCD.
// ---------------------------------------------------------------------------
template <bool FIRST>
__global__ __launch_bounds__(512, 2) void lstm_step(
    const unsigned short* __restrict__ X,      // [SS][NN][256] bf16
    const unsigned short* __restrict__ Wcat,   // [2][1024][512] bf16
    const float* __restrict__ bperm,           // [2][1024]
    unsigned short* __restrict__ hping,        // [2 ping][2 dir][NN][256] bf16
    float* __restrict__ cstate,                // [2 dir][NN][256] f32
    float* __restrict__ hsum,                  // [NN] f32
    int s) {
    constexpr int NR = FIRST ? 8 : 16;
    const int b     = blockIdx.x;              // 0..255
    const int dir   = b & 1;
    const int nblk  = (b >> 3) & 3;            // 0..3 (256 gate cols each)
    const int mslab = (((b & 7) >> 1) << 3) | (b >> 5);   // 0..31
    const int m0    = mslab * 256;
    const int n0    = nblk * 256;

    const int t = dir ? (SS - 1 - s) : s;
    const unsigned short* Xt    = X + (size_t)t * NN * DD;
    const unsigned short* hprev = hping + ((size_t)((s & 1) * 2 + dir)) * NN * 256;
    unsigned short*       hnext = hping + ((size_t)((((s + 1) & 1) * 2) + dir)) * NN * 256;
    const unsigned short* W     = Wcat + (size_t)dir * RGATE * KKD;
    const float*          bp    = bperm + dir * RGATE;
    float*                cdir  = cstate + (size_t)dir * NN * 256;

    __shared__ __align__(16) char smem[131072];
    // A bufs: [0,64K) = 4 x 16K;  B bufs: [64K,128K) = 4 x 16K
    // epilogue scratch (34.8 KB) overlays [0, ...) after the K-loop.

    const int tid  = threadIdx.x;
    const int lane = tid & 63;
    const int w    = tid >> 6;        // 0..7
    const int wm   = w >> 1, wn = w & 1;
    const int quad = lane >> 4, l15 = lane & 15;
    const int jq   = lane & 3,  rl  = lane >> 2;

    // staging lane constants: lane covers LDS (row=base+(lane>>2), seg=lane&3)
    // which must hold global seg (lane&3) ^ ((row>>1)&3) = (lane&3)^((lane>>3)&3)
    const int srow  = lane >> 2;
    const int gsegl = (lane & 3) ^ ((lane >> 3) & 3);

    auto stage = [&](int rr, int buf) {
        const int k0 = (rr & 7) * 32;                      // col within X or h
        const unsigned short* Asrc = (rr < 8) ? Xt : hprev;
        char* Ad = smem + buf * 16384;
        char* Bd = smem + 65536 + buf * 16384;
        #pragma unroll
        for (int i = 0; i < 2; ++i) {
            const int lr = w * 32 + i * 16 + srow;         // local row 0..255
            async_copy16(Asrc + (size_t)(m0 + lr) * DD + k0 + gsegl * 8,
                         (void*)(Ad + (w * 32 + i * 16) * 64));
            async_copy16(W + (size_t)(n0 + lr) * KKD + rr * 32 + gsegl * 8,
                         (void*)(Bd + (w * 32 + i * 16) * 64));
        }
    };

    f32x4 acc[4][8];
    #pragma unroll
    for (int i = 0; i < 4; ++i)
        #pragma unroll
        for (int j = 0; j < 8; ++j) acc[i][j] = f32x4{0.f, 0.f, 0.f, 0.f};

    const int sA = (quad ^ ((l15 >> 1) & 3)) * 16;   // frag-read seg byte offset

    auto krnd = [&](int cb) {
        const char* Ab = smem + cb * 16384;
        const char* Bb = smem + 65536 + cb * 16384;
        short8 af[4], bfr[8];
        #pragma unroll
        for (int mt = 0; mt < 4; ++mt)
            af[mt] = *(const short8*)(Ab + (wm * 64 + mt * 16 + l15) * 64 + sA);
        #pragma unroll
        for (int nt = 0; nt < 8; ++nt)
            bfr[nt] = *(const short8*)(Bb + (wn * 128 + nt * 16 + l15) * 64 + sA);
        #pragma unroll
        for (int mt = 0; mt < 4; ++mt)
            #pragma unroll
            for (int nt = 0; nt < 8; ++nt)
                acc[mt][nt] = __builtin_amdgcn_mfma_f32_16x16x32_bf16(
                    af[mt], bfr[nt], acc[mt][nt], 0, 0, 0);
    };

    // ---- K-loop: 4-buffer pipeline, counted vmcnt, no main-loop drain ----
    // Invariant at top of round r: issued stages 0..r+2 (prologue 3 + one
    // per prior round); vmcnt(8) retires everything through stage(r).
    stage(0, 0);
    stage(1, 1);
    stage(2, 2);
    #pragma unroll
    for (int r = 0; r < NR - 3; ++r) {
        asm volatile("s_waitcnt vmcnt(8)" ::: "memory");
        asm volatile("s_barrier" ::: "memory");   // buf (r&3) proven for all waves
        krnd(r & 3);
        stage(r + 3, (r + 3) & 3);   // -> buf (r-1)&3; readers passed barrier above
    }
    // tail rounds NR-3, NR-2, NR-1 (NR%4==0 -> buf indices 1,2,3)
    asm volatile("s_waitcnt vmcnt(8)" ::: "memory");
    asm volatile("s_barrier" ::: "memory");
    krnd(1);
    asm volatile("s_waitcnt vmcnt(4)" ::: "memory");
    asm volatile("s_barrier" ::: "memory");
    krnd(2);
    asm volatile("s_waitcnt vmcnt(0)" ::: "memory");
    asm volatile("s_barrier" ::: "memory");
    krnd(3);
    asm volatile("s_barrier" ::: "memory");       // epilogue overlays bufs

    // ---- epilogue: regroup gates (C/D -> unit-quads) via wave-private LDS ----
    float* my = (float*)smem + w * 1088;   // 16 x 68 floats per wave (34.8 KB)
    float hs[4] = {0.f, 0.f, 0.f, 0.f};

    #pragma unroll
    for (int half = 0; half < 2; ++half) {
        const int j0 = nblk * 64 + wn * 32 + half * 16 + jq * 4;  // global unit
        f32x4 bias4[4];
        #pragma unroll
        for (int jj = 0; jj < 4; ++jj)
            bias4[jj] = *(const f32x4*)(bp + 4 * (j0 + jj));
        #pragma unroll
        for (int mt = 0; mt < 4; ++mt) {
            #pragma unroll
            for (int nt = 0; nt < 4; ++nt) {
                const int ntg = half * 4 + nt;
                #pragma unroll
                for (int v = 0; v < 4; ++v)
                    my[(quad * 4 + v) * 68 + nt * 16 + l15] = acc[mt][ntg][v];
            }
            asm volatile("s_waitcnt lgkmcnt(0)" ::: "memory");
            const int mg = m0 + wm * 64 + mt * 16 + rl;
            float* cptr = cdir + (size_t)mg * 256 + j0;
            f32x4 cold;
            if constexpr (!FIRST) cold = *(const f32x4*)cptr;
            else                  cold = f32x4{0.f, 0.f, 0.f, 0.f};
            f32x4 cnew;
            ushort4 hp;
            float lsum = 0.f;
            #pragma unroll
            for (int jj = 0; jj < 4; ++jj) {
                f32x4 g  = *(const f32x4*)(my + rl * 68 + (jq * 4 + jj) * 4);
                f32x4 bb = bias4[jj];
                const float gi = sigm(g.x + bb.x);   // i
                const float gf = sigm(g.y + bb.y);   // f
                const float gg = tanh_(g.z + bb.z);  // g
                const float go = sigm(g.w + bb.w);   // o
                const float cn = gf * cold[jj] + gi * gg;
                cnew[jj] = cn;
                const float hv = go * tanh_(cn);
                lsum += hv;
                ((unsigned short*)&hp)[jj] = f2bf(hv);
            }
            *(f32x4*)cptr = cnew;
            *(ushort4*)(hnext + (size_t)mg * 256 + j0) = hp;
            hs[mt] += lsum;
        }
    }

    // per-row partial sums -> one atomic per (wave, row)
    #pragma unroll
    for (int mt = 0; mt < 4; ++mt) {
        float v = hs[mt];
        v += __shfl_xor(v, 1);
        v += __shfl_xor(v, 2);
        if (jq == 0) atomicAdd(&hsum[m0 + wm * 64 + mt * 16 + rl], v);
    }
}

__global__ void bcast_out(const float* __restrict__ hsum, float* __restrict__ out) {
    const int n = blockIdx.x;
    const float v = hsum[n] * (1.0f / 512.0f);
    float2 p; p.x = v; p.y = v;
    ((float2*)(out + (size_t)n * 512))[threadIdx.x] = p;
}

extern "C" void kernel_launch(void* const* d_in, const int* in_sizes, int n_in,
                              void* d_out, int out_size, void* d_ws, size_t ws_size,
                              hipStream_t stream) {
    const float* emb  = (const float*)d_in[0];
    const float* wihf = (const float*)d_in[1];
    const float* whhf = (const float*)d_in[2];
    const float* bf   = (const float*)d_in[3];
    const float* wihb = (const float*)d_in[4];
    const float* whhb = (const float*)d_in[5];
    const float* bb   = (const float*)d_in[6];
    const int*   idx  = (const int*)d_in[7];
    float* out = (float*)d_out;

    // workspace layout (bytes)
    char* ws = (char*)d_ws;
    unsigned short* X     = (unsigned short*)(ws);               // 83,886,080  X[t][n][256] bf16
    unsigned short* Wcat  = (unsigned short*)(ws + 83886080);    //  2,097,152  [2][1024][512] bf16
    float*          bperm = (float*)(ws + 85983232);             //      8,192  [2][1024] f32
    unsigned short* hping = (unsigned short*)(ws + 85991424);    // 16,777,216  [2][2][8192][256] bf16
    float*          cst   = (float*)(ws + 102768640);            // 16,777,216  [2][8192][256] f32
    float*          hsum  = (float*)(ws + 119545856);            //     32,768  [8192] f32
    // total: 119,578,624 B

    // s==0 skips all h/c reads -> only hsum needs zeroing
    hipMemsetAsync(hsum, 0, 32768, stream);

    convert_w<<<4096, 256, 0, stream>>>(wihf, whhf, bf, wihb, whhb, bb, Wcat, bperm);
    gather_x<<<2560, 256, 0, stream>>>(emb, idx, X);
    lstm_step<true><<<256, 512, 0, stream>>>(X, Wcat, bperm, hping, cst, hsum, 0);
    for (int s = 1; s < SS; ++s)
        lstm_step<false><<<256, 512, 0, stream>>>(X, Wcat, bperm, hping, cst, hsum, s);
    bcast_out<<<NN, 256, 0, stream>>>(hsum, out);
}